// Round 15
// baseline (604.836 us; speedup 1.0000x reference)
//
#include <hip/hip_runtime.h>
#include <math.h>

#define EMB 64
static constexpr float INV_SQRT_DK = 0.17677669529663687f; // 1/sqrt(32)

#define NBK 512           // KG bucket blocks
#define NBU 192           // UI bucket blocks
#define P3_PROJ 1024      // proj-role blocks in K1 (streaming || streaming)
#define PROJ2_BLOCKS 2048
#define PSHIFT 9          // 512-node partitions
#define PRANGE 512
#define CAPK 14336        // per-partition bucket capacity (mean ~10.2k + 40 sigma)
#define CAPU 14336

typedef unsigned uint2v __attribute__((ext_vector_type(2)));

__device__ inline unsigned short f2bf(float f) {
    union { float f; unsigned u; } v; v.f = f;
    unsigned r = v.u + 0x7FFF + ((v.u >> 16) & 1);   // round-to-nearest-even
    return (unsigned short)(r >> 16);
}
__device__ inline float bfhi(unsigned w) {           // high 16 bits as bf16
    union { float f; unsigned u; } v; v.u = w & 0xFFFF0000u; return v.f;
}
__device__ inline float bflo(unsigned w) {           // low 16 bits as bf16
    union { float f; unsigned u; } v; v.u = w << 16; return v.f;
}
__device__ inline float bf2f(unsigned short b) {
    union { float f; unsigned u; } v; v.u = ((unsigned)b) << 16; return v.f;
}

// ---- hop-1 proj rows: packed=(bf16(e@W)<<16)|bf16(e); also e_bf=bf16(e) for UI ----
__device__ inline void proj_rows(const float* __restrict__ e, const float* __restrict__ Wl,
                                 unsigned* __restrict__ packed, unsigned short* __restrict__ e_bf,
                                 int n, int wid, int nw, int lane) {
    for (int r = wid; r < n; r += nw) {
        float x = e[(size_t)r * EMB + lane];
        float acc = 0.f;
#pragma unroll
        for (int k = 0; k < 64; ++k) {
            float ek = __shfl(x, k, 64);
            acc += ek * Wl[k * 64 + lane];
        }
        unsigned eb = f2bf(x);
        size_t ix = (size_t)r * EMB + lane;
        packed[ix] = (((unsigned)f2bf(acc)) << 16) | eb;
        e_bf[ix] = (unsigned short)eb;
    }
}

// ---- hop-2 proj from bf16 normalized rows ----
__global__ void __launch_bounds__(256) proj2b_kernel(
        const unsigned short* __restrict__ enorm, const float* __restrict__ W,
        unsigned* __restrict__ packed2, int n) {
    __shared__ float Wl[64 * 64];
    for (int i = threadIdx.x; i < 64 * 64; i += 256) Wl[i] = W[i];
    __syncthreads();
    int lane = threadIdx.x & 63;
    int wid = blockIdx.x * 4 + (threadIdx.x >> 6);
    int nw = PROJ2_BLOCKS * 4;
    for (int r = wid; r < n; r += nw) {
        unsigned short eb = enorm[(size_t)r * EMB + lane];
        float x = bf2f(eb);
        float acc = 0.f;
#pragma unroll
        for (int k = 0; k < 64; ++k) {
            float ek = __shfl(x, k, 64);
            acc += ek * Wl[k * 64 + lane];
        }
        packed2[(size_t)r * EMB + lane] = (((unsigned)f2bf(acc)) << 16) | eb;
    }
}

// ---- K1: fixed-capacity partition bucketing MERGED with proj (both streaming) ----
// KG record: local(9) << 21 | type(4) << 17 | tail(17). Partition base = p*CAP (no scan).
__global__ void __launch_bounds__(256) k1_bucket_proj(
        const int* __restrict__ head, const int* __restrict__ tail,
        const int* __restrict__ etype, int E,
        int* __restrict__ pdK, unsigned* __restrict__ bktK,
        const int* __restrict__ iu, const int* __restrict__ ii,
        const float* __restrict__ w, int EI,
        int* __restrict__ pdU, uint2v* __restrict__ bktU,
        const float* __restrict__ e_in, const float* __restrict__ W,
        unsigned* __restrict__ packed, unsigned short* __restrict__ e_bf,
        int n_ent, int nPartH, int nPartU) {
    __shared__ float sh[64 * 64];
    int b = blockIdx.x;
    if (b >= NBK + NBU) {
        // ---- proj role: grid-stride over entity rows ----
        for (int i = threadIdx.x; i < 64 * 64; i += 256) sh[i] = W[i];
        __syncthreads();
        int lane = threadIdx.x & 63;
        int wid = (b - (NBK + NBU)) * 4 + (threadIdx.x >> 6);
        proj_rows(e_in, sh, packed, e_bf, n_ent, wid, P3_PROJ * 4, lane);
        return;
    }
    int* lc = (int*)sh;
    lc[threadIdx.x] = 0;
    __syncthreads();
    if (b < NBK) {
        int chunk = (E + NBK - 1) / NBK;
        int lo = b * chunk, hi = min(lo + chunk, E);
        for (int e = lo + (int)threadIdx.x; e < hi; e += 256)
            atomicAdd(&lc[__builtin_nontemporal_load(&head[e]) >> PSHIFT], 1);
        __syncthreads();
        if ((int)threadIdx.x < nPartH)
            lc[threadIdx.x] = threadIdx.x * CAPK + atomicAdd(&pdK[threadIdx.x], lc[threadIdx.x]);
        __syncthreads();
        for (int e = lo + (int)threadIdx.x; e < hi; e += 256) {
            int h = __builtin_nontemporal_load(&head[e]);
            int tl = __builtin_nontemporal_load(&tail[e]);
            int ty = __builtin_nontemporal_load(&etype[e]);
            int pos = atomicAdd(&lc[h >> PSHIFT], 1);
            unsigned r = ((unsigned)(h & (PRANGE - 1)) << 21) | (unsigned)(tl | ((ty - 1) << 17));
            __builtin_nontemporal_store(r, &bktK[pos]);
        }
    } else {
        int bb = b - NBK;
        int chunk = (EI + NBU - 1) / NBU;
        int lo = bb * chunk, hi = min(lo + chunk, EI);
        for (int e = lo + (int)threadIdx.x; e < hi; e += 256)
            atomicAdd(&lc[__builtin_nontemporal_load(&iu[e]) >> PSHIFT], 1);
        __syncthreads();
        if ((int)threadIdx.x < nPartU)
            lc[threadIdx.x] = threadIdx.x * CAPU + atomicAdd(&pdU[threadIdx.x], lc[threadIdx.x]);
        __syncthreads();
        for (int e = lo + (int)threadIdx.x; e < hi; e += 256) {
            int u = __builtin_nontemporal_load(&iu[e]);
            int it = __builtin_nontemporal_load(&ii[e]);
            float wv = __builtin_nontemporal_load(&w[e]);
            int pos = atomicAdd(&lc[u >> PSHIFT], 1);
            unsigned wq = (unsigned)(wv * 32767.f + 0.5f);
            uint2v r; r.x = (unsigned)it | (wq << 17); r.y = (unsigned)u;
            __builtin_nontemporal_store(r, &bktU[pos]);
        }
    }
}

// ---- K2: per-partition LDS counting sort -> node-sorted col[] + off[] ----
// 512 threads: hist/scatter passes use all 8 waves; the pair-scan uses the first 256.
__global__ void __launch_bounds__(512) k2_sort(
        const unsigned* __restrict__ bktK, const int* __restrict__ pdK,
        int* __restrict__ off_h, int* __restrict__ col_h, int n_ent, int nPartH, int E,
        const uint2v* __restrict__ bktU, const int* __restrict__ pdU,
        int* __restrict__ off_u, unsigned* __restrict__ col_ui, int n_usr, int nPartU, int EI) {
    __shared__ int hist[PRANGE];
    __shared__ int wsum[8];
    int t = threadIdx.x;
    int lane = t & 63, wv = t >> 6;
    int b = blockIdx.x;
    bool isU = b >= nPartH;
    int p = isU ? b - nPartH : b;
    const int* pd = isU ? pdU : pdK;
    int cnt = min(pd[p], isU ? CAPU : CAPK);
    // S_p = sum of partition counts before p (pd arrays are 256 ints, zero beyond nPart)
    int contrib = (t < p) ? pd[t] : 0;
#pragma unroll
    for (int m = 1; m <= 32; m <<= 1) contrib += __shfl_xor(contrib, m, 64);
    if (lane == 0) wsum[wv] = contrib;
    hist[t] = 0;                        // 512 threads cover all 512 bins
    __syncthreads();
    int Sp = wsum[0] + wsum[1] + wsum[2] + wsum[3] + wsum[4] + wsum[5] + wsum[6] + wsum[7];
    // pass 1: histogram of node-locals
    if (!isU) {
        const unsigned* bk = bktK + (size_t)p * CAPK;
        for (int i = t; i < cnt; i += 512)
            atomicAdd(&hist[__builtin_nontemporal_load(&bk[i]) >> 21], 1);
    } else {
        const uint2v* bu = bktU + (size_t)p * CAPU;
        int plo0 = p << PSHIFT;
        for (int i = t; i < cnt; i += 512) {
            uint2v r = __builtin_nontemporal_load(&bu[i]);
            atomicAdd(&hist[(int)r.y - plo0], 1);
        }
    }
    __syncthreads();
    // exclusive scan of 512 bins (pairs per thread, first 256 threads)
    int v0 = 0, v1 = 0, ps = 0, incl = 0;
    if (t < 256) { v0 = hist[2 * t]; v1 = hist[2 * t + 1]; ps = v0 + v1; incl = ps; }
#pragma unroll
    for (int d = 1; d <= 32; d <<= 1) { int x = __shfl_up(incl, d, 64); if (lane >= d) incl += x; }
    __syncthreads();                   // hist reads done before cursor overwrite
    if (t < 256 && lane == 63) wsum[wv] = incl;
    __syncthreads();
    int plo = p << PSHIFT;
    if (t < 256) {
        int woff = 0;
        for (int i = 0; i < wv; ++i) woff += wsum[i];
        int ex = incl - ps + woff;     // exclusive over pairs
        int nmax = isU ? n_usr : n_ent;
        int* off = isU ? off_u : off_h;
        if (plo + 2 * t < nmax)     off[plo + 2 * t]     = Sp + ex;
        if (plo + 2 * t + 1 < nmax) off[plo + 2 * t + 1] = Sp + ex + v0;
        hist[2 * t] = Sp + ex;         // reuse hist as write cursors
        hist[2 * t + 1] = Sp + ex + v0;
    }
    if (b == 0 && t == 0) off_h[n_ent] = E;
    if (b == nPartH && t == 0) off_u[n_usr] = EI;
    __syncthreads();
    // pass 2: scatter into node-sorted col
    if (!isU) {
        const unsigned* bk = bktK + (size_t)p * CAPK;
        for (int i = t; i < cnt; i += 512) {
            unsigned r = __builtin_nontemporal_load(&bk[i]);
            int pos = atomicAdd(&hist[r >> 21], 1);
            col_h[pos] = (int)(r & 0x1FFFFFu);
        }
    } else {
        const uint2v* bu = bktU + (size_t)p * CAPU;
        for (int i = t; i < cnt; i += 512) {
            uint2v r = __builtin_nontemporal_load(&bu[i]);
            int pos = atomicAdd(&hist[(int)r.y - plo], 1);
            col_ui[pos] = r.x;
        }
    }
}

// ------- fused agg, 4 dims/lane 4 edges/wave: KG attention + UI weighted agg -------
template <bool HOP1>
__global__ void __launch_bounds__(256) agg_fused_kernel(
        const unsigned* __restrict__ pk,          // KG gather table for this hop
        const unsigned short* __restrict__ ebT,   // UI value table (hop1: e_bf, hop2: enorm)
        unsigned short* __restrict__ enorm_out,   // HOP1: bf16 normalized rows
        const float* __restrict__ rel_emb,
        const int* __restrict__ off_h, const int* __restrict__ col_h,
        const int* __restrict__ off_u, const unsigned* __restrict__ col_ui,
        const float* __restrict__ e_base, float* __restrict__ e_res, int n_ent,
        const float* __restrict__ u_base, float* __restrict__ u_res,
        int n_usr, int kgBlocks, int totalBlocks) {
    __shared__ float4 relS4[16 * 16];             // rel_emb as float4 rows
    int bid = blockIdx.x;
    // Bresenham interleave of kg-role and ui-role blocks
    size_t lo = (size_t)bid * kgBlocks / totalBlocks;
    size_t hi = (size_t)(bid + 1) * kgBlocks / totalBlocks;
    int lane = threadIdx.x & 63;
    int wslot = threadIdx.x >> 6;
    int slot = lane >> 4;
    int sub  = lane & 15;
    int dd   = sub * 4;

    if (hi > lo) {
        // ---------------- KG entity block ----------------
        for (int i = threadIdx.x; i < 16 * 16; i += blockDim.x)
            relS4[i] = ((const float4*)rel_emb)[i];
        __syncthreads();
        int wid = (int)lo * 4 + wslot;
        if (wid >= n_ent) return;
        int s = off_h[wid], e = off_h[wid + 1];
        uint4 qw = *(const uint4*)&pk[(size_t)wid * EMB + dd];
        float q0 = bfhi(qw.x), q1 = bfhi(qw.y), q2 = bfhi(qw.z), q3 = bfhi(qw.w);
        float num0 = 0.f, num1 = 0.f, num2 = 0.f, num3 = 0.f, den = 0.f;
        for (int j = s; j < e; j += 4) {
            int jj = j + slot;
            bool invd = jj >= e;
            if (invd) jj = e - 1;
            int p = __builtin_nontemporal_load(&col_h[jj]);
            int tt = p & 131071;
            int rr = p >> 17;
            uint4 w = *(const uint4*)&pk[(size_t)tt * EMB + dd];
            float4 rl = relS4[rr * 16 + sub];
            float prod = q0 * rl.x * bfhi(w.x);
            prod = fmaf(q1 * rl.y, bfhi(w.y), prod);
            prod = fmaf(q2 * rl.z, bfhi(w.z), prod);
            prod = fmaf(q3 * rl.w, bfhi(w.w), prod);
            prod += __shfl_xor(prod, 1, 64);
            prod += __shfl_xor(prod, 2, 64);
            prod += __shfl_xor(prod, 4, 64);
            float ex = __expf(prod * INV_SQRT_DK);
            if (invd) ex = 0.f;
            den += ex;
            num0 = fmaf(ex * rl.x, bflo(w.x), num0);
            num1 = fmaf(ex * rl.y, bflo(w.y), num1);
            num2 = fmaf(ex * rl.z, bflo(w.z), num2);
            num3 = fmaf(ex * rl.w, bflo(w.w), num3);
        }
        // combine the 4 edge slots (once per node)
        den  += __shfl_xor(den, 16, 64);  den  += __shfl_xor(den, 32, 64);
        num0 += __shfl_xor(num0, 16, 64); num0 += __shfl_xor(num0, 32, 64);
        num1 += __shfl_xor(num1, 16, 64); num1 += __shfl_xor(num1, 32, 64);
        num2 += __shfl_xor(num2, 16, 64); num2 += __shfl_xor(num2, 32, 64);
        num3 += __shfl_xor(num3, 16, 64); num3 += __shfl_xor(num3, 32, 64);
        float dinv = (e > s) ? 1.f / den : 0.f;   // deferred softmax division
        float v0 = num0 * dinv, v1 = num1 * dinv, v2 = num2 * dinv, v3 = num3 * dinv;
        float ss = fmaf(v0, v0, fmaf(v1, v1, fmaf(v2, v2, v3 * v3)));
        ss += __shfl_xor(ss, 1, 64);
        ss += __shfl_xor(ss, 2, 64);
        ss += __shfl_xor(ss, 4, 64);
        ss += __shfl_xor(ss, 8, 64);
        float rn = 1.f / fmaxf(sqrtf(ss), 1e-12f);
        float o0 = v0 * rn, o1 = v1 * rn, o2 = v2 * rn, o3 = v3 * rn;
        if (slot == 0) {
            size_t ix = (size_t)wid * EMB + dd;
            if (HOP1) {
                ushort4 nb; nb.x = f2bf(o0); nb.y = f2bf(o1); nb.z = f2bf(o2); nb.w = f2bf(o3);
                *(ushort4*)&enorm_out[ix] = nb;
                float4 bv = *(const float4*)&e_base[ix];
                *(float4*)&e_res[ix] = make_float4(bv.x + o0, bv.y + o1, bv.z + o2, bv.w + o3);
            } else {
                float4 rv = *(const float4*)&e_res[ix];
                *(float4*)&e_res[ix] = make_float4(rv.x + o0, rv.y + o1, rv.z + o2, rv.w + o3);
            }
        }
    } else {
        // ---------------- UI user block (bf16 value table) ----------------
        int wid = (bid - (int)lo) * 4 + wslot;
        if (wid >= n_usr) return;
        int s = off_u[wid], e = off_u[wid + 1];
        float a0 = 0.f, a1 = 0.f, a2 = 0.f, a3 = 0.f;
        for (int j = s; j < e; j += 4) {
            int jj = j + slot;
            bool invd = jj >= e;
            if (invd) jj = e - 1;
            unsigned c = __builtin_nontemporal_load(&col_ui[jj]);
            float wv = invd ? 0.f : (c >> 17) * (1.f / 32767.f);
            ushort4 v = *(const ushort4*)&ebT[(size_t)(c & 131071u) * EMB + dd];
            a0 = fmaf(wv, bf2f(v.x), a0);
            a1 = fmaf(wv, bf2f(v.y), a1);
            a2 = fmaf(wv, bf2f(v.z), a2);
            a3 = fmaf(wv, bf2f(v.w), a3);
        }
        a0 += __shfl_xor(a0, 16, 64); a0 += __shfl_xor(a0, 32, 64);
        a1 += __shfl_xor(a1, 16, 64); a1 += __shfl_xor(a1, 32, 64);
        a2 += __shfl_xor(a2, 16, 64); a2 += __shfl_xor(a2, 32, 64);
        a3 += __shfl_xor(a3, 16, 64); a3 += __shfl_xor(a3, 32, 64);
        float ss = fmaf(a0, a0, fmaf(a1, a1, fmaf(a2, a2, a3 * a3)));
        ss += __shfl_xor(ss, 1, 64);
        ss += __shfl_xor(ss, 2, 64);
        ss += __shfl_xor(ss, 4, 64);
        ss += __shfl_xor(ss, 8, 64);
        float rn = 1.f / fmaxf(sqrtf(ss), 1e-12f);
        float o0 = a0 * rn, o1 = a1 * rn, o2 = a2 * rn, o3 = a3 * rn;
        if (slot == 0) {
            size_t ix = (size_t)wid * EMB + dd;
            if (HOP1) {
                float4 bv = *(const float4*)&u_base[ix];
                *(float4*)&u_res[ix] = make_float4(bv.x + o0, bv.y + o1, bv.z + o2, bv.w + o3);
            } else {
                float4 rv = *(const float4*)&u_res[ix];
                *(float4*)&u_res[ix] = make_float4(rv.x + o0, rv.y + o1, rv.z + o2, rv.w + o3);
            }
        }
    }
}

extern "C" void kernel_launch(void* const* d_in, const int* in_sizes, int n_in,
                              void* d_out, int out_size, void* d_ws, size_t ws_size,
                              hipStream_t stream) {
    const float* user_emb   = (const float*)d_in[0];
    const float* entity_emb = (const float*)d_in[1];
    const int*   edge_index = (const int*)d_in[2];   // [2, E]
    const int*   edge_type  = (const int*)d_in[3];   // [E]
    const int*   inter_edge = (const int*)d_in[4];   // [2, EI]
    const float* inter_w    = (const float*)d_in[5]; // [EI]
    const float* W_Q        = (const float*)d_in[6]; // [64,64]
    const float* rel_emb    = (const float*)d_in[7]; // [16,64]

    const int E     = in_sizes[3];
    const int EI    = in_sizes[5];
    const int n_ent = in_sizes[1] / EMB;
    const int n_usr = in_sizes[0] / EMB;

    const int* head = edge_index;
    const int* tail = edge_index + E;
    const int* iu   = inter_edge;
    const int* ii   = inter_edge + EI;

    const int nPartH = (n_ent + PRANGE - 1) >> PSHIFT;   // 196 (<=256)
    const int nPartU = (n_usr + PRANGE - 1) >> PSHIFT;   // 98  (<=256)

    // ---- workspace layout ----
    char* ws = (char*)d_ws;
    unsigned* packed  = (unsigned*)ws;         ws += (size_t)n_ent * EMB * 4;   // hop-1 table
    unsigned* packed2 = (unsigned*)ws;         ws += (size_t)n_ent * EMB * 4;   // hop-2 table
    unsigned short* enorm = (unsigned short*)ws; ws += (size_t)n_ent * EMB * 2; // agg1 out / hop2 UI
    unsigned short* e_bf  = (unsigned short*)ws; ws += (size_t)n_ent * EMB * 2; // hop1 UI values
    int*      col_h  = (int*)ws;               ws += (size_t)E * 4;
    unsigned* col_ui = (unsigned*)ws;          ws += (size_t)EI * 4;
    int*   off_h = (int*)ws;                   ws += (size_t)(n_ent + 1) * 4;
    int*   off_u = (int*)ws;                   ws += (size_t)(n_usr + 1) * 4;
    int*   pdK   = (int*)ws;                   ws += 256 * 4;   // zeroed partition counts
    int*   pdU   = (int*)ws;                   ws += 256 * 4;
    // fixed-capacity buckets overlay packed2 (dead until proj2b writes it)
    unsigned* bktK = (unsigned*)packed2;                         // nPartH*CAPK*4  (~11.2 MB)
    uint2v*   bktU = (uint2v*)(bktK + (size_t)nPartH * CAPK);    // nPartU*CAPU*8  (~11.2 MB)

    float* e_res = (float*)d_out;
    float* u_res = e_res + (size_t)n_ent * EMB;

    // ---- CSR build: fixed-capacity bucket sort (no global hist, no scans) ----
    hipMemsetAsync(pdK, 0, 512 * 4, stream);
    k1_bucket_proj<<<NBK + NBU + P3_PROJ, 256, 0, stream>>>(
        head, tail, edge_type, E, pdK, bktK,
        iu, ii, inter_w, EI, pdU, bktU,
        entity_emb, W_Q, packed, e_bf, n_ent, nPartH, nPartU);
    k2_sort<<<nPartH + nPartU, 512, 0, stream>>>(
        bktK, pdK, off_h, col_h, n_ent, nPartH, E,
        bktU, pdU, off_u, col_ui, n_usr, nPartU, EI);

    const int kgBlocks = (n_ent + 3) / 4;
    const int uiBlocks = (n_usr + 3) / 4;
    const int totalBlocks = kgBlocks + uiBlocks;

    // ---- hop 1 (KG table = packed, UI table = e_bf; emits enorm) ----
    agg_fused_kernel<true><<<totalBlocks, 256, 0, stream>>>(
        packed, e_bf, enorm, rel_emb, off_h, col_h, off_u, col_ui,
        entity_emb, e_res, n_ent, user_emb, u_res, n_usr, kgBlocks, totalBlocks);

    // ---- hop-2 proj from bf16 norm rows ----
    proj2b_kernel<<<PROJ2_BLOCKS, 256, 0, stream>>>(enorm, W_Q, packed2, n_ent);

    // ---- hop 2 (KG table = packed2, UI table = enorm) ----
    agg_fused_kernel<false><<<totalBlocks, 256, 0, stream>>>(
        packed2, enorm, nullptr, rel_emb, off_h, col_h, off_u, col_ui,
        nullptr, e_res, n_ent, nullptr, u_res, n_usr, kgBlocks, totalBlocks);
}

// Round 16
// 565.186 us; speedup vs baseline: 1.0702x; 1.0702x over previous
//
#include <hip/hip_runtime.h>
#include <math.h>

#define EMB 64
static constexpr float INV_SQRT_DK = 0.17677669529663687f; // 1/sqrt(32)

#define NBK 128           // KG bucket blocks (long dense runs: ~320 B per (block,partition))
#define NBU 48            // UI bucket blocks (~1.7 KB runs)
#define P3_PROJ 1024      // proj-role blocks in K1 (streaming || streaming)
#define PROJ2_BLOCKS 2048
#define PSHIFT 9          // 512-node partitions
#define PRANGE 512
#define CAPK 14336        // per-partition bucket capacity (mean ~10.2k + 40 sigma)
#define CAPU 14336

typedef unsigned uint2v __attribute__((ext_vector_type(2)));

__device__ inline unsigned short f2bf(float f) {
    union { float f; unsigned u; } v; v.f = f;
    unsigned r = v.u + 0x7FFF + ((v.u >> 16) & 1);   // round-to-nearest-even
    return (unsigned short)(r >> 16);
}
__device__ inline float bfhi(unsigned w) {           // high 16 bits as bf16
    union { float f; unsigned u; } v; v.u = w & 0xFFFF0000u; return v.f;
}
__device__ inline float bflo(unsigned w) {           // low 16 bits as bf16
    union { float f; unsigned u; } v; v.u = w << 16; return v.f;
}
__device__ inline float bf2f(unsigned short b) {
    union { float f; unsigned u; } v; v.u = ((unsigned)b) << 16; return v.f;
}

// ---- hop-1 proj rows: packed=(bf16(e@W)<<16)|bf16(e); also e_bf=bf16(e) for UI ----
__device__ inline void proj_rows(const float* __restrict__ e, const float* __restrict__ Wl,
                                 unsigned* __restrict__ packed, unsigned short* __restrict__ e_bf,
                                 int n, int wid, int nw, int lane) {
    for (int r = wid; r < n; r += nw) {
        float x = e[(size_t)r * EMB + lane];
        float acc = 0.f;
#pragma unroll
        for (int k = 0; k < 64; ++k) {
            float ek = __shfl(x, k, 64);
            acc += ek * Wl[k * 64 + lane];
        }
        unsigned eb = f2bf(x);
        size_t ix = (size_t)r * EMB + lane;
        packed[ix] = (((unsigned)f2bf(acc)) << 16) | eb;
        e_bf[ix] = (unsigned short)eb;
    }
}

// ---- hop-2 proj from bf16 normalized rows ----
__global__ void __launch_bounds__(256) proj2b_kernel(
        const unsigned short* __restrict__ enorm, const float* __restrict__ W,
        unsigned* __restrict__ packed2, int n) {
    __shared__ float Wl[64 * 64];
    for (int i = threadIdx.x; i < 64 * 64; i += 256) Wl[i] = W[i];
    __syncthreads();
    int lane = threadIdx.x & 63;
    int wid = blockIdx.x * 4 + (threadIdx.x >> 6);
    int nw = PROJ2_BLOCKS * 4;
    for (int r = wid; r < n; r += nw) {
        unsigned short eb = enorm[(size_t)r * EMB + lane];
        float x = bf2f(eb);
        float acc = 0.f;
#pragma unroll
        for (int k = 0; k < 64; ++k) {
            float ek = __shfl(x, k, 64);
            acc += ek * Wl[k * 64 + lane];
        }
        packed2[(size_t)r * EMB + lane] = (((unsigned)f2bf(acc)) << 16) | eb;
    }
}

// ---- K1: fixed-capacity partition bucketing MERGED with proj (both streaming) ----
// KG record: local(9) << 21 | type(4) << 17 | tail(17). Partition base = p*CAP (no scan).
__global__ void __launch_bounds__(256) k1_bucket_proj(
        const int* __restrict__ head, const int* __restrict__ tail,
        const int* __restrict__ etype, int E,
        int* __restrict__ pdK, unsigned* __restrict__ bktK,
        const int* __restrict__ iu, const int* __restrict__ ii,
        const float* __restrict__ w, int EI,
        int* __restrict__ pdU, uint2v* __restrict__ bktU,
        const float* __restrict__ e_in, const float* __restrict__ W,
        unsigned* __restrict__ packed, unsigned short* __restrict__ e_bf,
        int n_ent, int nPartH, int nPartU) {
    __shared__ float sh[64 * 64];
    int b = blockIdx.x;
    if (b >= NBK + NBU) {
        // ---- proj role: grid-stride over entity rows ----
        for (int i = threadIdx.x; i < 64 * 64; i += 256) sh[i] = W[i];
        __syncthreads();
        int lane = threadIdx.x & 63;
        int wid = (b - (NBK + NBU)) * 4 + (threadIdx.x >> 6);
        proj_rows(e_in, sh, packed, e_bf, n_ent, wid, P3_PROJ * 4, lane);
        return;
    }
    int* lc = (int*)sh;
    lc[threadIdx.x] = 0;
    __syncthreads();
    if (b < NBK) {
        int chunk = (E + NBK - 1) / NBK;
        int lo = b * chunk, hi = min(lo + chunk, E);
        for (int e = lo + (int)threadIdx.x; e < hi; e += 256)
            atomicAdd(&lc[__builtin_nontemporal_load(&head[e]) >> PSHIFT], 1);
        __syncthreads();
        if ((int)threadIdx.x < nPartH)
            lc[threadIdx.x] = threadIdx.x * CAPK + atomicAdd(&pdK[threadIdx.x], lc[threadIdx.x]);
        __syncthreads();
        for (int e = lo + (int)threadIdx.x; e < hi; e += 256) {
            int h = __builtin_nontemporal_load(&head[e]);
            int tl = __builtin_nontemporal_load(&tail[e]);
            int ty = __builtin_nontemporal_load(&etype[e]);
            int pos = atomicAdd(&lc[h >> PSHIFT], 1);
            unsigned r = ((unsigned)(h & (PRANGE - 1)) << 21) | (unsigned)(tl | ((ty - 1) << 17));
            __builtin_nontemporal_store(r, &bktK[pos]);
        }
    } else {
        int bb = b - NBK;
        int chunk = (EI + NBU - 1) / NBU;
        int lo = bb * chunk, hi = min(lo + chunk, EI);
        for (int e = lo + (int)threadIdx.x; e < hi; e += 256)
            atomicAdd(&lc[__builtin_nontemporal_load(&iu[e]) >> PSHIFT], 1);
        __syncthreads();
        if ((int)threadIdx.x < nPartU)
            lc[threadIdx.x] = threadIdx.x * CAPU + atomicAdd(&pdU[threadIdx.x], lc[threadIdx.x]);
        __syncthreads();
        for (int e = lo + (int)threadIdx.x; e < hi; e += 256) {
            int u = __builtin_nontemporal_load(&iu[e]);
            int it = __builtin_nontemporal_load(&ii[e]);
            float wv = __builtin_nontemporal_load(&w[e]);
            int pos = atomicAdd(&lc[u >> PSHIFT], 1);
            unsigned wq = (unsigned)(wv * 32767.f + 0.5f);
            uint2v r; r.x = (unsigned)it | (wq << 17); r.y = (unsigned)u;
            __builtin_nontemporal_store(r, &bktU[pos]);
        }
    }
}

// ---- K2: per-partition LDS counting sort -> node-sorted col[] + off[] ----
// 512 threads: hist/scatter passes use all 8 waves; the pair-scan uses the first 256.
__global__ void __launch_bounds__(512) k2_sort(
        const unsigned* __restrict__ bktK, const int* __restrict__ pdK,
        int* __restrict__ off_h, int* __restrict__ col_h, int n_ent, int nPartH, int E,
        const uint2v* __restrict__ bktU, const int* __restrict__ pdU,
        int* __restrict__ off_u, unsigned* __restrict__ col_ui, int n_usr, int nPartU, int EI) {
    __shared__ int hist[PRANGE];
    __shared__ int wsum[8];
    int t = threadIdx.x;
    int lane = t & 63, wv = t >> 6;
    int b = blockIdx.x;
    bool isU = b >= nPartH;
    int p = isU ? b - nPartH : b;
    const int* pd = isU ? pdU : pdK;
    int cnt = min(pd[p], isU ? CAPU : CAPK);
    // S_p = sum of partition counts before p (pd arrays are 256 ints, zero beyond nPart)
    int contrib = (t < p) ? pd[t] : 0;
#pragma unroll
    for (int m = 1; m <= 32; m <<= 1) contrib += __shfl_xor(contrib, m, 64);
    if (lane == 0) wsum[wv] = contrib;
    hist[t] = 0;                        // 512 threads cover all 512 bins
    __syncthreads();
    int Sp = wsum[0] + wsum[1] + wsum[2] + wsum[3] + wsum[4] + wsum[5] + wsum[6] + wsum[7];
    // pass 1: histogram of node-locals
    if (!isU) {
        const unsigned* bk = bktK + (size_t)p * CAPK;
        for (int i = t; i < cnt; i += 512)
            atomicAdd(&hist[__builtin_nontemporal_load(&bk[i]) >> 21], 1);
    } else {
        const uint2v* bu = bktU + (size_t)p * CAPU;
        int plo0 = p << PSHIFT;
        for (int i = t; i < cnt; i += 512) {
            uint2v r = __builtin_nontemporal_load(&bu[i]);
            atomicAdd(&hist[(int)r.y - plo0], 1);
        }
    }
    __syncthreads();
    // exclusive scan of 512 bins (pairs per thread, first 256 threads)
    int v0 = 0, v1 = 0, ps = 0, incl = 0;
    if (t < 256) { v0 = hist[2 * t]; v1 = hist[2 * t + 1]; ps = v0 + v1; incl = ps; }
#pragma unroll
    for (int d = 1; d <= 32; d <<= 1) { int x = __shfl_up(incl, d, 64); if (lane >= d) incl += x; }
    __syncthreads();                   // hist reads done before cursor overwrite
    if (t < 256 && lane == 63) wsum[wv] = incl;
    __syncthreads();
    int plo = p << PSHIFT;
    if (t < 256) {
        int woff = 0;
        for (int i = 0; i < wv; ++i) woff += wsum[i];
        int ex = incl - ps + woff;     // exclusive over pairs
        int nmax = isU ? n_usr : n_ent;
        int* off = isU ? off_u : off_h;
        if (plo + 2 * t < nmax)     off[plo + 2 * t]     = Sp + ex;
        if (plo + 2 * t + 1 < nmax) off[plo + 2 * t + 1] = Sp + ex + v0;
        hist[2 * t] = Sp + ex;         // reuse hist as write cursors
        hist[2 * t + 1] = Sp + ex + v0;
    }
    if (b == 0 && t == 0) off_h[n_ent] = E;
    if (b == nPartH && t == 0) off_u[n_usr] = EI;
    __syncthreads();
    // pass 2: scatter into node-sorted col
    if (!isU) {
        const unsigned* bk = bktK + (size_t)p * CAPK;
        for (int i = t; i < cnt; i += 512) {
            unsigned r = __builtin_nontemporal_load(&bk[i]);
            int pos = atomicAdd(&hist[r >> 21], 1);
            col_h[pos] = (int)(r & 0x1FFFFFu);
        }
    } else {
        const uint2v* bu = bktU + (size_t)p * CAPU;
        for (int i = t; i < cnt; i += 512) {
            uint2v r = __builtin_nontemporal_load(&bu[i]);
            int pos = atomicAdd(&hist[(int)r.y - plo], 1);
            col_ui[pos] = r.x;
        }
    }
}

// ------- fused agg, 4 dims/lane 4 edges/wave: KG attention + UI weighted agg -------
template <bool HOP1>
__global__ void __launch_bounds__(256) agg_fused_kernel(
        const unsigned* __restrict__ pk,          // KG gather table for this hop
        const unsigned short* __restrict__ ebT,   // UI value table (hop1: e_bf, hop2: enorm)
        unsigned short* __restrict__ enorm_out,   // HOP1: bf16 normalized rows
        const float* __restrict__ rel_emb,
        const int* __restrict__ off_h, const int* __restrict__ col_h,
        const int* __restrict__ off_u, const unsigned* __restrict__ col_ui,
        const float* __restrict__ e_base, float* __restrict__ e_res, int n_ent,
        const float* __restrict__ u_base, float* __restrict__ u_res,
        int n_usr, int kgBlocks, int totalBlocks) {
    __shared__ float4 relS4[16 * 16];             // rel_emb as float4 rows
    int bid = blockIdx.x;
    // Bresenham interleave of kg-role and ui-role blocks
    size_t lo = (size_t)bid * kgBlocks / totalBlocks;
    size_t hi = (size_t)(bid + 1) * kgBlocks / totalBlocks;
    int lane = threadIdx.x & 63;
    int wslot = threadIdx.x >> 6;
    int slot = lane >> 4;
    int sub  = lane & 15;
    int dd   = sub * 4;

    if (hi > lo) {
        // ---------------- KG entity block ----------------
        for (int i = threadIdx.x; i < 16 * 16; i += blockDim.x)
            relS4[i] = ((const float4*)rel_emb)[i];
        __syncthreads();
        int wid = (int)lo * 4 + wslot;
        if (wid >= n_ent) return;
        int s = off_h[wid], e = off_h[wid + 1];
        uint4 qw = *(const uint4*)&pk[(size_t)wid * EMB + dd];
        float q0 = bfhi(qw.x), q1 = bfhi(qw.y), q2 = bfhi(qw.z), q3 = bfhi(qw.w);
        float num0 = 0.f, num1 = 0.f, num2 = 0.f, num3 = 0.f, den = 0.f;
        for (int j = s; j < e; j += 4) {
            int jj = j + slot;
            bool invd = jj >= e;
            if (invd) jj = e - 1;
            int p = __builtin_nontemporal_load(&col_h[jj]);
            int tt = p & 131071;
            int rr = p >> 17;
            uint4 w = *(const uint4*)&pk[(size_t)tt * EMB + dd];
            float4 rl = relS4[rr * 16 + sub];
            float prod = q0 * rl.x * bfhi(w.x);
            prod = fmaf(q1 * rl.y, bfhi(w.y), prod);
            prod = fmaf(q2 * rl.z, bfhi(w.z), prod);
            prod = fmaf(q3 * rl.w, bfhi(w.w), prod);
            prod += __shfl_xor(prod, 1, 64);
            prod += __shfl_xor(prod, 2, 64);
            prod += __shfl_xor(prod, 4, 64);
            float ex = __expf(prod * INV_SQRT_DK);
            if (invd) ex = 0.f;
            den += ex;
            num0 = fmaf(ex * rl.x, bflo(w.x), num0);
            num1 = fmaf(ex * rl.y, bflo(w.y), num1);
            num2 = fmaf(ex * rl.z, bflo(w.z), num2);
            num3 = fmaf(ex * rl.w, bflo(w.w), num3);
        }
        // combine the 4 edge slots (once per node)
        den  += __shfl_xor(den, 16, 64);  den  += __shfl_xor(den, 32, 64);
        num0 += __shfl_xor(num0, 16, 64); num0 += __shfl_xor(num0, 32, 64);
        num1 += __shfl_xor(num1, 16, 64); num1 += __shfl_xor(num1, 32, 64);
        num2 += __shfl_xor(num2, 16, 64); num2 += __shfl_xor(num2, 32, 64);
        num3 += __shfl_xor(num3, 16, 64); num3 += __shfl_xor(num3, 32, 64);
        float dinv = (e > s) ? 1.f / den : 0.f;   // deferred softmax division
        float v0 = num0 * dinv, v1 = num1 * dinv, v2 = num2 * dinv, v3 = num3 * dinv;
        float ss = fmaf(v0, v0, fmaf(v1, v1, fmaf(v2, v2, v3 * v3)));
        ss += __shfl_xor(ss, 1, 64);
        ss += __shfl_xor(ss, 2, 64);
        ss += __shfl_xor(ss, 4, 64);
        ss += __shfl_xor(ss, 8, 64);
        float rn = 1.f / fmaxf(sqrtf(ss), 1e-12f);
        float o0 = v0 * rn, o1 = v1 * rn, o2 = v2 * rn, o3 = v3 * rn;
        if (slot == 0) {
            size_t ix = (size_t)wid * EMB + dd;
            if (HOP1) {
                ushort4 nb; nb.x = f2bf(o0); nb.y = f2bf(o1); nb.z = f2bf(o2); nb.w = f2bf(o3);
                *(ushort4*)&enorm_out[ix] = nb;
                float4 bv = *(const float4*)&e_base[ix];
                *(float4*)&e_res[ix] = make_float4(bv.x + o0, bv.y + o1, bv.z + o2, bv.w + o3);
            } else {
                float4 rv = *(const float4*)&e_res[ix];
                *(float4*)&e_res[ix] = make_float4(rv.x + o0, rv.y + o1, rv.z + o2, rv.w + o3);
            }
        }
    } else {
        // ---------------- UI user block (bf16 value table) ----------------
        int wid = (bid - (int)lo) * 4 + wslot;
        if (wid >= n_usr) return;
        int s = off_u[wid], e = off_u[wid + 1];
        float a0 = 0.f, a1 = 0.f, a2 = 0.f, a3 = 0.f;
        for (int j = s; j < e; j += 4) {
            int jj = j + slot;
            bool invd = jj >= e;
            if (invd) jj = e - 1;
            unsigned c = __builtin_nontemporal_load(&col_ui[jj]);
            float wv = invd ? 0.f : (c >> 17) * (1.f / 32767.f);
            ushort4 v = *(const ushort4*)&ebT[(size_t)(c & 131071u) * EMB + dd];
            a0 = fmaf(wv, bf2f(v.x), a0);
            a1 = fmaf(wv, bf2f(v.y), a1);
            a2 = fmaf(wv, bf2f(v.z), a2);
            a3 = fmaf(wv, bf2f(v.w), a3);
        }
        a0 += __shfl_xor(a0, 16, 64); a0 += __shfl_xor(a0, 32, 64);
        a1 += __shfl_xor(a1, 16, 64); a1 += __shfl_xor(a1, 32, 64);
        a2 += __shfl_xor(a2, 16, 64); a2 += __shfl_xor(a2, 32, 64);
        a3 += __shfl_xor(a3, 16, 64); a3 += __shfl_xor(a3, 32, 64);
        float ss = fmaf(a0, a0, fmaf(a1, a1, fmaf(a2, a2, a3 * a3)));
        ss += __shfl_xor(ss, 1, 64);
        ss += __shfl_xor(ss, 2, 64);
        ss += __shfl_xor(ss, 4, 64);
        ss += __shfl_xor(ss, 8, 64);
        float rn = 1.f / fmaxf(sqrtf(ss), 1e-12f);
        float o0 = a0 * rn, o1 = a1 * rn, o2 = a2 * rn, o3 = a3 * rn;
        if (slot == 0) {
            size_t ix = (size_t)wid * EMB + dd;
            if (HOP1) {
                float4 bv = *(const float4*)&u_base[ix];
                *(float4*)&u_res[ix] = make_float4(bv.x + o0, bv.y + o1, bv.z + o2, bv.w + o3);
            } else {
                float4 rv = *(const float4*)&u_res[ix];
                *(float4*)&u_res[ix] = make_float4(rv.x + o0, rv.y + o1, rv.z + o2, rv.w + o3);
            }
        }
    }
}

extern "C" void kernel_launch(void* const* d_in, const int* in_sizes, int n_in,
                              void* d_out, int out_size, void* d_ws, size_t ws_size,
                              hipStream_t stream) {
    const float* user_emb   = (const float*)d_in[0];
    const float* entity_emb = (const float*)d_in[1];
    const int*   edge_index = (const int*)d_in[2];   // [2, E]
    const int*   edge_type  = (const int*)d_in[3];   // [E]
    const int*   inter_edge = (const int*)d_in[4];   // [2, EI]
    const float* inter_w    = (const float*)d_in[5]; // [EI]
    const float* W_Q        = (const float*)d_in[6]; // [64,64]
    const float* rel_emb    = (const float*)d_in[7]; // [16,64]

    const int E     = in_sizes[3];
    const int EI    = in_sizes[5];
    const int n_ent = in_sizes[1] / EMB;
    const int n_usr = in_sizes[0] / EMB;

    const int* head = edge_index;
    const int* tail = edge_index + E;
    const int* iu   = inter_edge;
    const int* ii   = inter_edge + EI;

    const int nPartH = (n_ent + PRANGE - 1) >> PSHIFT;   // 196 (<=256)
    const int nPartU = (n_usr + PRANGE - 1) >> PSHIFT;   // 98  (<=256)

    // ---- workspace layout ----
    char* ws = (char*)d_ws;
    unsigned* packed  = (unsigned*)ws;         ws += (size_t)n_ent * EMB * 4;   // hop-1 table
    unsigned* packed2 = (unsigned*)ws;         ws += (size_t)n_ent * EMB * 4;   // hop-2 table
    unsigned short* enorm = (unsigned short*)ws; ws += (size_t)n_ent * EMB * 2; // agg1 out / hop2 UI
    unsigned short* e_bf  = (unsigned short*)ws; ws += (size_t)n_ent * EMB * 2; // hop1 UI values
    int*      col_h  = (int*)ws;               ws += (size_t)E * 4;
    unsigned* col_ui = (unsigned*)ws;          ws += (size_t)EI * 4;
    int*   off_h = (int*)ws;                   ws += (size_t)(n_ent + 1) * 4;
    int*   off_u = (int*)ws;                   ws += (size_t)(n_usr + 1) * 4;
    int*   pdK   = (int*)ws;                   ws += 256 * 4;   // zeroed partition counts
    int*   pdU   = (int*)ws;                   ws += 256 * 4;
    // fixed-capacity buckets overlay packed2 (dead until proj2b writes it)
    unsigned* bktK = (unsigned*)packed2;                         // nPartH*CAPK*4  (~11.2 MB)
    uint2v*   bktU = (uint2v*)(bktK + (size_t)nPartH * CAPK);    // nPartU*CAPU*8  (~11.2 MB)

    float* e_res = (float*)d_out;
    float* u_res = e_res + (size_t)n_ent * EMB;

    // ---- CSR build: fixed-capacity bucket sort (no global hist, no scans) ----
    hipMemsetAsync(pdK, 0, 512 * 4, stream);
    k1_bucket_proj<<<NBK + NBU + P3_PROJ, 256, 0, stream>>>(
        head, tail, edge_type, E, pdK, bktK,
        iu, ii, inter_w, EI, pdU, bktU,
        entity_emb, W_Q, packed, e_bf, n_ent, nPartH, nPartU);
    k2_sort<<<nPartH + nPartU, 512, 0, stream>>>(
        bktK, pdK, off_h, col_h, n_ent, nPartH, E,
        bktU, pdU, off_u, col_ui, n_usr, nPartU, EI);

    const int kgBlocks = (n_ent + 3) / 4;
    const int uiBlocks = (n_usr + 3) / 4;
    const int totalBlocks = kgBlocks + uiBlocks;

    // ---- hop 1 (KG table = packed, UI table = e_bf; emits enorm) ----
    agg_fused_kernel<true><<<totalBlocks, 256, 0, stream>>>(
        packed, e_bf, enorm, rel_emb, off_h, col_h, off_u, col_ui,
        entity_emb, e_res, n_ent, user_emb, u_res, n_usr, kgBlocks, totalBlocks);

    // ---- hop-2 proj from bf16 norm rows ----
    proj2b_kernel<<<PROJ2_BLOCKS, 256, 0, stream>>>(enorm, W_Q, packed2, n_ent);

    // ---- hop 2 (KG table = packed2, UI table = enorm) ----
    agg_fused_kernel<false><<<totalBlocks, 256, 0, stream>>>(
        packed2, enorm, nullptr, rel_emb, off_h, col_h, off_u, col_ui,
        nullptr, e_res, n_ent, nullptr, u_res, n_usr, kgBlocks, totalBlocks);
}

// Round 17
// 524.911 us; speedup vs baseline: 1.1523x; 1.0767x over previous
//
#include <hip/hip_runtime.h>
#include <math.h>

#define EMB 64
static constexpr float INV_SQRT_DK = 0.17677669529663687f; // 1/sqrt(32)

#define NBK 128           // KG bucket blocks (long dense runs: ~320 B per (block,partition))
#define NBU 48            // UI bucket blocks (~1.7 KB runs)
#define P3_PROJ 1024      // proj-role blocks in K1 (streaming || streaming)
#define PROJ2_BLOCKS 2048
#define PSHIFT 9          // 512-node partitions
#define PRANGE 512
#define CAPK 14336        // per-partition bucket capacity (mean ~10.2k + 40 sigma)
#define CAPU 14336

typedef unsigned uint2v __attribute__((ext_vector_type(2)));

__device__ inline unsigned short f2bf(float f) {
    union { float f; unsigned u; } v; v.f = f;
    unsigned r = v.u + 0x7FFF + ((v.u >> 16) & 1);   // round-to-nearest-even
    return (unsigned short)(r >> 16);
}
__device__ inline float bfhi(unsigned w) {           // high 16 bits as bf16
    union { float f; unsigned u; } v; v.u = w & 0xFFFF0000u; return v.f;
}
__device__ inline float bflo(unsigned w) {           // low 16 bits as bf16
    union { float f; unsigned u; } v; v.u = w << 16; return v.f;
}
__device__ inline float bf2f(unsigned short b) {
    union { float f; unsigned u; } v; v.u = ((unsigned)b) << 16; return v.f;
}

// ---- hop-1 proj rows: packed=(bf16(e@W)<<16)|bf16(e); also e_bf=bf16(e) for UI ----
__device__ inline void proj_rows(const float* __restrict__ e, const float* __restrict__ Wl,
                                 unsigned* __restrict__ packed, unsigned short* __restrict__ e_bf,
                                 int n, int wid, int nw, int lane) {
    for (int r = wid; r < n; r += nw) {
        float x = e[(size_t)r * EMB + lane];
        float acc = 0.f;
#pragma unroll
        for (int k = 0; k < 64; ++k) {
            float ek = __shfl(x, k, 64);
            acc += ek * Wl[k * 64 + lane];
        }
        unsigned eb = f2bf(x);
        size_t ix = (size_t)r * EMB + lane;
        packed[ix] = (((unsigned)f2bf(acc)) << 16) | eb;
        e_bf[ix] = (unsigned short)eb;
    }
}

// ---- hop-2 proj from bf16 normalized rows ----
__global__ void __launch_bounds__(256) proj2b_kernel(
        const unsigned short* __restrict__ enorm, const float* __restrict__ W,
        unsigned* __restrict__ packed2, int n) {
    __shared__ float Wl[64 * 64];
    for (int i = threadIdx.x; i < 64 * 64; i += 256) Wl[i] = W[i];
    __syncthreads();
    int lane = threadIdx.x & 63;
    int wid = blockIdx.x * 4 + (threadIdx.x >> 6);
    int nw = PROJ2_BLOCKS * 4;
    for (int r = wid; r < n; r += nw) {
        unsigned short eb = enorm[(size_t)r * EMB + lane];
        float x = bf2f(eb);
        float acc = 0.f;
#pragma unroll
        for (int k = 0; k < 64; ++k) {
            float ek = __shfl(x, k, 64);
            acc += ek * Wl[k * 64 + lane];
        }
        packed2[(size_t)r * EMB + lane] = (((unsigned)f2bf(acc)) << 16) | eb;
    }
}

// ---- K1: fixed-capacity partition bucketing MERGED with proj (both streaming) ----
// KG record: local(9) << 21 | type(4) << 17 | tail(17). Partition base = p*CAP (no scan).
__global__ void __launch_bounds__(256) k1_bucket_proj(
        const int* __restrict__ head, const int* __restrict__ tail,
        const int* __restrict__ etype, int E,
        int* __restrict__ pdK, unsigned* __restrict__ bktK,
        const int* __restrict__ iu, const int* __restrict__ ii,
        const float* __restrict__ w, int EI,
        int* __restrict__ pdU, uint2v* __restrict__ bktU,
        const float* __restrict__ e_in, const float* __restrict__ W,
        unsigned* __restrict__ packed, unsigned short* __restrict__ e_bf,
        int n_ent, int nPartH, int nPartU) {
    __shared__ float sh[64 * 64];
    int b = blockIdx.x;
    if (b >= NBK + NBU) {
        // ---- proj role: grid-stride over entity rows ----
        for (int i = threadIdx.x; i < 64 * 64; i += 256) sh[i] = W[i];
        __syncthreads();
        int lane = threadIdx.x & 63;
        int wid = (b - (NBK + NBU)) * 4 + (threadIdx.x >> 6);
        proj_rows(e_in, sh, packed, e_bf, n_ent, wid, P3_PROJ * 4, lane);
        return;
    }
    int* lc = (int*)sh;
    lc[threadIdx.x] = 0;
    __syncthreads();
    if (b < NBK) {
        int chunk = (E + NBK - 1) / NBK;
        int lo = b * chunk, hi = min(lo + chunk, E);
        for (int e = lo + (int)threadIdx.x; e < hi; e += 256)
            atomicAdd(&lc[__builtin_nontemporal_load(&head[e]) >> PSHIFT], 1);
        __syncthreads();
        if ((int)threadIdx.x < nPartH)
            lc[threadIdx.x] = threadIdx.x * CAPK + atomicAdd(&pdK[threadIdx.x], lc[threadIdx.x]);
        __syncthreads();
        for (int e = lo + (int)threadIdx.x; e < hi; e += 256) {
            int h = __builtin_nontemporal_load(&head[e]);
            int tl = __builtin_nontemporal_load(&tail[e]);
            int ty = __builtin_nontemporal_load(&etype[e]);
            int pos = atomicAdd(&lc[h >> PSHIFT], 1);
            unsigned r = ((unsigned)(h & (PRANGE - 1)) << 21) | (unsigned)(tl | ((ty - 1) << 17));
            __builtin_nontemporal_store(r, &bktK[pos]);
        }
    } else {
        int bb = b - NBK;
        int chunk = (EI + NBU - 1) / NBU;
        int lo = bb * chunk, hi = min(lo + chunk, EI);
        for (int e = lo + (int)threadIdx.x; e < hi; e += 256)
            atomicAdd(&lc[__builtin_nontemporal_load(&iu[e]) >> PSHIFT], 1);
        __syncthreads();
        if ((int)threadIdx.x < nPartU)
            lc[threadIdx.x] = threadIdx.x * CAPU + atomicAdd(&pdU[threadIdx.x], lc[threadIdx.x]);
        __syncthreads();
        for (int e = lo + (int)threadIdx.x; e < hi; e += 256) {
            int u = __builtin_nontemporal_load(&iu[e]);
            int it = __builtin_nontemporal_load(&ii[e]);
            float wv = __builtin_nontemporal_load(&w[e]);
            int pos = atomicAdd(&lc[u >> PSHIFT], 1);
            unsigned wq = (unsigned)(wv * 32767.f + 0.5f);
            uint2v r; r.x = (unsigned)it | (wq << 17); r.y = (unsigned)u;
            __builtin_nontemporal_store(r, &bktU[pos]);
        }
    }
}

// ---- K2: per-partition LDS counting sort -> node-sorted col[] + off[] ----
// 512 threads: hist/scatter passes use all 8 waves; the pair-scan uses the first 256.
__global__ void __launch_bounds__(512) k2_sort(
        const unsigned* __restrict__ bktK, const int* __restrict__ pdK,
        int* __restrict__ off_h, int* __restrict__ col_h, int n_ent, int nPartH, int E,
        const uint2v* __restrict__ bktU, const int* __restrict__ pdU,
        int* __restrict__ off_u, unsigned* __restrict__ col_ui, int n_usr, int nPartU, int EI) {
    __shared__ int hist[PRANGE];
    __shared__ int wsum[8];
    int t = threadIdx.x;
    int lane = t & 63, wv = t >> 6;
    int b = blockIdx.x;
    bool isU = b >= nPartH;
    int p = isU ? b - nPartH : b;
    const int* pd = isU ? pdU : pdK;
    int cnt = min(pd[p], isU ? CAPU : CAPK);
    // S_p = sum of partition counts before p (pd arrays are 256 ints, zero beyond nPart)
    int contrib = (t < p) ? pd[t] : 0;
#pragma unroll
    for (int m = 1; m <= 32; m <<= 1) contrib += __shfl_xor(contrib, m, 64);
    if (lane == 0) wsum[wv] = contrib;
    hist[t] = 0;                        // 512 threads cover all 512 bins
    __syncthreads();
    int Sp = wsum[0] + wsum[1] + wsum[2] + wsum[3] + wsum[4] + wsum[5] + wsum[6] + wsum[7];
    // pass 1: histogram of node-locals
    if (!isU) {
        const unsigned* bk = bktK + (size_t)p * CAPK;
        for (int i = t; i < cnt; i += 512)
            atomicAdd(&hist[__builtin_nontemporal_load(&bk[i]) >> 21], 1);
    } else {
        const uint2v* bu = bktU + (size_t)p * CAPU;
        int plo0 = p << PSHIFT;
        for (int i = t; i < cnt; i += 512) {
            uint2v r = __builtin_nontemporal_load(&bu[i]);
            atomicAdd(&hist[(int)r.y - plo0], 1);
        }
    }
    __syncthreads();
    // exclusive scan of 512 bins (pairs per thread, first 256 threads)
    int v0 = 0, v1 = 0, ps = 0, incl = 0;
    if (t < 256) { v0 = hist[2 * t]; v1 = hist[2 * t + 1]; ps = v0 + v1; incl = ps; }
#pragma unroll
    for (int d = 1; d <= 32; d <<= 1) { int x = __shfl_up(incl, d, 64); if (lane >= d) incl += x; }
    __syncthreads();                   // hist reads done before cursor overwrite
    if (t < 256 && lane == 63) wsum[wv] = incl;
    __syncthreads();
    int plo = p << PSHIFT;
    if (t < 256) {
        int woff = 0;
        for (int i = 0; i < wv; ++i) woff += wsum[i];
        int ex = incl - ps + woff;     // exclusive over pairs
        int nmax = isU ? n_usr : n_ent;
        int* off = isU ? off_u : off_h;
        if (plo + 2 * t < nmax)     off[plo + 2 * t]     = Sp + ex;
        if (plo + 2 * t + 1 < nmax) off[plo + 2 * t + 1] = Sp + ex + v0;
        hist[2 * t] = Sp + ex;         // reuse hist as write cursors
        hist[2 * t + 1] = Sp + ex + v0;
    }
    if (b == 0 && t == 0) off_h[n_ent] = E;
    if (b == nPartH && t == 0) off_u[n_usr] = EI;
    __syncthreads();
    // pass 2: scatter into node-sorted col
    if (!isU) {
        const unsigned* bk = bktK + (size_t)p * CAPK;
        for (int i = t; i < cnt; i += 512) {
            unsigned r = __builtin_nontemporal_load(&bk[i]);
            int pos = atomicAdd(&hist[r >> 21], 1);
            col_h[pos] = (int)(r & 0x1FFFFFu);
        }
    } else {
        const uint2v* bu = bktU + (size_t)p * CAPU;
        for (int i = t; i < cnt; i += 512) {
            uint2v r = __builtin_nontemporal_load(&bu[i]);
            int pos = atomicAdd(&hist[(int)r.y - plo], 1);
            col_ui[pos] = r.x;
        }
    }
}

// ------- fused agg, 4 dims/lane 4 edges/wave: KG attention + UI weighted agg -------
template <bool HOP1>
__global__ void __launch_bounds__(256) agg_fused_kernel(
        const unsigned* __restrict__ pk,          // KG gather table for this hop
        const unsigned short* __restrict__ ebT,   // UI value table (hop1: e_bf, hop2: enorm)
        unsigned short* __restrict__ enorm_out,   // HOP1: bf16 normalized rows
        const float* __restrict__ rel_emb,
        const int* __restrict__ off_h, const int* __restrict__ col_h,
        const int* __restrict__ off_u, const unsigned* __restrict__ col_ui,
        const float* __restrict__ e_base, float* __restrict__ e_res, int n_ent,
        const float* __restrict__ u_base, float* __restrict__ u_res,
        int n_usr, int kgBlocks, int totalBlocks) {
    __shared__ float4 relS4[16 * 16];             // rel_emb as float4 rows
    int bid = blockIdx.x;
    // Bresenham interleave of kg-role and ui-role blocks
    size_t lo = (size_t)bid * kgBlocks / totalBlocks;
    size_t hi = (size_t)(bid + 1) * kgBlocks / totalBlocks;
    int lane = threadIdx.x & 63;
    int wslot = threadIdx.x >> 6;
    int slot = lane >> 4;
    int sub  = lane & 15;
    int dd   = sub * 4;

    if (hi > lo) {
        // ---------------- KG entity block ----------------
        for (int i = threadIdx.x; i < 16 * 16; i += blockDim.x)
            relS4[i] = ((const float4*)rel_emb)[i];
        __syncthreads();
        int wid = (int)lo * 4 + wslot;
        if (wid >= n_ent) return;
        int s = off_h[wid], e = off_h[wid + 1];
        uint4 qw = *(const uint4*)&pk[(size_t)wid * EMB + dd];
        float q0 = bfhi(qw.x), q1 = bfhi(qw.y), q2 = bfhi(qw.z), q3 = bfhi(qw.w);
        float num0 = 0.f, num1 = 0.f, num2 = 0.f, num3 = 0.f, den = 0.f;
        for (int j = s; j < e; j += 4) {
            int jj = j + slot;
            bool invd = jj >= e;
            if (invd) jj = e - 1;
            int p = col_h[jj];
            int tt = p & 131071;
            int rr = p >> 17;
            uint4 w = *(const uint4*)&pk[(size_t)tt * EMB + dd];
            float4 rl = relS4[rr * 16 + sub];
            float prod = q0 * rl.x * bfhi(w.x);
            prod = fmaf(q1 * rl.y, bfhi(w.y), prod);
            prod = fmaf(q2 * rl.z, bfhi(w.z), prod);
            prod = fmaf(q3 * rl.w, bfhi(w.w), prod);
            prod += __shfl_xor(prod, 1, 64);
            prod += __shfl_xor(prod, 2, 64);
            prod += __shfl_xor(prod, 4, 64);
            float ex = __expf(prod * INV_SQRT_DK);
            if (invd) ex = 0.f;
            den += ex;
            num0 = fmaf(ex * rl.x, bflo(w.x), num0);
            num1 = fmaf(ex * rl.y, bflo(w.y), num1);
            num2 = fmaf(ex * rl.z, bflo(w.z), num2);
            num3 = fmaf(ex * rl.w, bflo(w.w), num3);
        }
        // combine the 4 edge slots (once per node)
        den  += __shfl_xor(den, 16, 64);  den  += __shfl_xor(den, 32, 64);
        num0 += __shfl_xor(num0, 16, 64); num0 += __shfl_xor(num0, 32, 64);
        num1 += __shfl_xor(num1, 16, 64); num1 += __shfl_xor(num1, 32, 64);
        num2 += __shfl_xor(num2, 16, 64); num2 += __shfl_xor(num2, 32, 64);
        num3 += __shfl_xor(num3, 16, 64); num3 += __shfl_xor(num3, 32, 64);
        float dinv = (e > s) ? 1.f / den : 0.f;   // deferred softmax division
        float v0 = num0 * dinv, v1 = num1 * dinv, v2 = num2 * dinv, v3 = num3 * dinv;
        float ss = fmaf(v0, v0, fmaf(v1, v1, fmaf(v2, v2, v3 * v3)));
        ss += __shfl_xor(ss, 1, 64);
        ss += __shfl_xor(ss, 2, 64);
        ss += __shfl_xor(ss, 4, 64);
        ss += __shfl_xor(ss, 8, 64);
        float rn = 1.f / fmaxf(sqrtf(ss), 1e-12f);
        float o0 = v0 * rn, o1 = v1 * rn, o2 = v2 * rn, o3 = v3 * rn;
        if (slot == 0) {
            size_t ix = (size_t)wid * EMB + dd;
            if (HOP1) {
                ushort4 nb; nb.x = f2bf(o0); nb.y = f2bf(o1); nb.z = f2bf(o2); nb.w = f2bf(o3);
                *(ushort4*)&enorm_out[ix] = nb;
                float4 bv = *(const float4*)&e_base[ix];
                *(float4*)&e_res[ix] = make_float4(bv.x + o0, bv.y + o1, bv.z + o2, bv.w + o3);
            } else {
                float4 rv = *(const float4*)&e_res[ix];
                *(float4*)&e_res[ix] = make_float4(rv.x + o0, rv.y + o1, rv.z + o2, rv.w + o3);
            }
        }
    } else {
        // ---------------- UI user block (bf16 value table) ----------------
        int wid = (bid - (int)lo) * 4 + wslot;
        if (wid >= n_usr) return;
        int s = off_u[wid], e = off_u[wid + 1];
        float a0 = 0.f, a1 = 0.f, a2 = 0.f, a3 = 0.f;
        for (int j = s; j < e; j += 4) {
            int jj = j + slot;
            bool invd = jj >= e;
            if (invd) jj = e - 1;
            unsigned c = col_ui[jj];
            float wv = invd ? 0.f : (c >> 17) * (1.f / 32767.f);
            ushort4 v = *(const ushort4*)&ebT[(size_t)(c & 131071u) * EMB + dd];
            a0 = fmaf(wv, bf2f(v.x), a0);
            a1 = fmaf(wv, bf2f(v.y), a1);
            a2 = fmaf(wv, bf2f(v.z), a2);
            a3 = fmaf(wv, bf2f(v.w), a3);
        }
        a0 += __shfl_xor(a0, 16, 64); a0 += __shfl_xor(a0, 32, 64);
        a1 += __shfl_xor(a1, 16, 64); a1 += __shfl_xor(a1, 32, 64);
        a2 += __shfl_xor(a2, 16, 64); a2 += __shfl_xor(a2, 32, 64);
        a3 += __shfl_xor(a3, 16, 64); a3 += __shfl_xor(a3, 32, 64);
        float ss = fmaf(a0, a0, fmaf(a1, a1, fmaf(a2, a2, a3 * a3)));
        ss += __shfl_xor(ss, 1, 64);
        ss += __shfl_xor(ss, 2, 64);
        ss += __shfl_xor(ss, 4, 64);
        ss += __shfl_xor(ss, 8, 64);
        float rn = 1.f / fmaxf(sqrtf(ss), 1e-12f);
        float o0 = a0 * rn, o1 = a1 * rn, o2 = a2 * rn, o3 = a3 * rn;
        if (slot == 0) {
            size_t ix = (size_t)wid * EMB + dd;
            if (HOP1) {
                float4 bv = *(const float4*)&u_base[ix];
                *(float4*)&u_res[ix] = make_float4(bv.x + o0, bv.y + o1, bv.z + o2, bv.w + o3);
            } else {
                float4 rv = *(const float4*)&u_res[ix];
                *(float4*)&u_res[ix] = make_float4(rv.x + o0, rv.y + o1, rv.z + o2, rv.w + o3);
            }
        }
    }
}

extern "C" void kernel_launch(void* const* d_in, const int* in_sizes, int n_in,
                              void* d_out, int out_size, void* d_ws, size_t ws_size,
                              hipStream_t stream) {
    const float* user_emb   = (const float*)d_in[0];
    const float* entity_emb = (const float*)d_in[1];
    const int*   edge_index = (const int*)d_in[2];   // [2, E]
    const int*   edge_type  = (const int*)d_in[3];   // [E]
    const int*   inter_edge = (const int*)d_in[4];   // [2, EI]
    const float* inter_w    = (const float*)d_in[5]; // [EI]
    const float* W_Q        = (const float*)d_in[6]; // [64,64]
    const float* rel_emb    = (const float*)d_in[7]; // [16,64]

    const int E     = in_sizes[3];
    const int EI    = in_sizes[5];
    const int n_ent = in_sizes[1] / EMB;
    const int n_usr = in_sizes[0] / EMB;

    const int* head = edge_index;
    const int* tail = edge_index + E;
    const int* iu   = inter_edge;
    const int* ii   = inter_edge + EI;

    const int nPartH = (n_ent + PRANGE - 1) >> PSHIFT;   // 196 (<=256)
    const int nPartU = (n_usr + PRANGE - 1) >> PSHIFT;   // 98  (<=256)

    // ---- workspace layout ----
    char* ws = (char*)d_ws;
    unsigned* packed  = (unsigned*)ws;         ws += (size_t)n_ent * EMB * 4;   // hop-1 table
    unsigned* packed2 = (unsigned*)ws;         ws += (size_t)n_ent * EMB * 4;   // hop-2 table
    unsigned short* enorm = (unsigned short*)ws; ws += (size_t)n_ent * EMB * 2; // agg1 out / hop2 UI
    unsigned short* e_bf  = (unsigned short*)ws; ws += (size_t)n_ent * EMB * 2; // hop1 UI values
    int*      col_h  = (int*)ws;               ws += (size_t)E * 4;
    unsigned* col_ui = (unsigned*)ws;          ws += (size_t)EI * 4;
    int*   off_h = (int*)ws;                   ws += (size_t)(n_ent + 1) * 4;
    int*   off_u = (int*)ws;                   ws += (size_t)(n_usr + 1) * 4;
    int*   pdK   = (int*)ws;                   ws += 256 * 4;   // zeroed partition counts
    int*   pdU   = (int*)ws;                   ws += 256 * 4;
    // fixed-capacity buckets overlay packed2 (dead until proj2b writes it)
    unsigned* bktK = (unsigned*)packed2;                         // nPartH*CAPK*4  (~11.2 MB)
    uint2v*   bktU = (uint2v*)(bktK + (size_t)nPartH * CAPK);    // nPartU*CAPU*8  (~11.2 MB)

    float* e_res = (float*)d_out;
    float* u_res = e_res + (size_t)n_ent * EMB;

    // ---- CSR build: fixed-capacity bucket sort (no global hist, no scans) ----
    hipMemsetAsync(pdK, 0, 512 * 4, stream);
    k1_bucket_proj<<<NBK + NBU + P3_PROJ, 256, 0, stream>>>(
        head, tail, edge_type, E, pdK, bktK,
        iu, ii, inter_w, EI, pdU, bktU,
        entity_emb, W_Q, packed, e_bf, n_ent, nPartH, nPartU);
    k2_sort<<<nPartH + nPartU, 512, 0, stream>>>(
        bktK, pdK, off_h, col_h, n_ent, nPartH, E,
        bktU, pdU, off_u, col_ui, n_usr, nPartU, EI);

    const int kgBlocks = (n_ent + 3) / 4;
    const int uiBlocks = (n_usr + 3) / 4;
    const int totalBlocks = kgBlocks + uiBlocks;

    // ---- hop 1 (KG table = packed, UI table = e_bf; emits enorm) ----
    agg_fused_kernel<true><<<totalBlocks, 256, 0, stream>>>(
        packed, e_bf, enorm, rel_emb, off_h, col_h, off_u, col_ui,
        entity_emb, e_res, n_ent, user_emb, u_res, n_usr, kgBlocks, totalBlocks);

    // ---- hop-2 proj from bf16 norm rows ----
    proj2b_kernel<<<PROJ2_BLOCKS, 256, 0, stream>>>(enorm, W_Q, packed2, n_ent);

    // ---- hop 2 (KG table = packed2, UI table = enorm) ----
    agg_fused_kernel<false><<<totalBlocks, 256, 0, stream>>>(
        packed2, enorm, nullptr, rel_emb, off_h, col_h, off_u, col_ui,
        nullptr, e_res, n_ent, nullptr, u_res, n_usr, kgBlocks, totalBlocks);
}